// Round 8
// baseline (563.162 us; speedup 1.0000x reference)
//
#include <hip/hip_runtime.h>

#define BS  16
#define TT  50
#define NN  100
#define OBSF 40
#define ACTF 8
#define HIDF 64
#define LATF 16

typedef __attribute__((ext_vector_type(8))) short bf16x8;
typedef __attribute__((ext_vector_type(4))) float f32x4;

__device__ __forceinline__ float sigmf(float x) { return 1.f / (1.f + __expf(-x)); }
__device__ __forceinline__ float tanh_fast(float x) { return 1.f - 2.f / (__expf(2.f * x) + 1.f); }
__device__ __forceinline__ short bf16s_rne(float a) {
    unsigned u = __float_as_uint(a); u += 0x7fffu + ((u >> 16) & 1u);
    return (short)(u >> 16);
}
__device__ __forceinline__ unsigned bf16pk_rne(float a, float b) {
    unsigned ua = __float_as_uint(a); ua += 0x7fffu + ((ua >> 16) & 1u);
    unsigned ub = __float_as_uint(b); ub += 0x7fffu + ((ub >> 16) & 1u);
    return (ua >> 16) | (ub & 0xffff0000u);
}

// ---------------------------------------------------------------- adj bitmask
__global__ void adjmask_kernel(const int* __restrict__ adj, unsigned long long* __restrict__ mask) {
    int n = threadIdx.x;
    if (n < NN) {
        unsigned long long w0 = 0ull, w1 = 0ull;
        for (int m = 0; m < 64; ++m)  if (adj[n * NN + m] > 0) w0 |= (1ull << m);
        for (int m = 64; m < NN; ++m) if (adj[n * NN + m] > 0) w1 |= (1ull << (m - 64));
        mask[2 * n] = w0; mask[2 * n + 1] = w1;
    }
}

// ---------------------------------------------------------------- embedding
__global__ void emb_kernel(const float* __restrict__ o, const float* __restrict__ ap,
                           const float* __restrict__ mk,
                           const float* __restrict__ Wobs, const float* __restrict__ bobs,
                           const float* __restrict__ Wpa, const float* __restrict__ bpa,
                           const float* __restrict__ Wmk, const float* __restrict__ bmk,
                           const float* __restrict__ idemb, float* __restrict__ emb) {
    int g = blockIdx.x;               // (b*T+t)*N + n
    int n = g % NN;
    int j = threadIdx.x;              // 0..63
    __shared__ float so[OBSF], sa[ACTF], sm[ACTF];
    if (j < OBSF) so[j] = o[(size_t)g * OBSF + j];
    if (j >= 40 && j < 48) sa[j - 40] = ap[(size_t)g * ACTF + (j - 40)];
    if (j >= 48 && j < 56) sm[j - 48] = mk[(size_t)g * ACTF + (j - 48)];
    __syncthreads();
    float acc = bobs[j] + bpa[j] + bmk[j] + idemb[n * HIDF + j];
    #pragma unroll
    for (int k = 0; k < OBSF; ++k) acc += so[k] * Wobs[k * HIDF + j];
    #pragma unroll
    for (int k = 0; k < ACTF; ++k) acc += sa[k] * Wpa[k * HIDF + j] + sm[k] * Wmk[k * HIDF + j];
    emb[(size_t)g * HIDF + j] = acc;
}

// ---------------------------------------------------------------- MFMA LSTM (round-7, kept)
__launch_bounds__(256)
__global__ void lstm_mfma_kernel(const float* __restrict__ emb,
                                 const float* __restrict__ Wih, const float* __restrict__ Whh,
                                 const float* __restrict__ bih, const float* __restrict__ bhh,
                                 float* __restrict__ xenc) {
    constexpr int GSTRIDE = 260;
    __shared__ __align__(16) float gbuf[16 * GSTRIDE];
    __shared__ __align__(16) short embt[2][16 * 72];
    __shared__ __align__(16) short hbuf[16 * 72];

    const int tid = threadIdx.x;
    const int wv = tid >> 6, lane = tid & 63, q = lane >> 4, c = lane & 15;

    const int seq = tid >> 4;
    const int part = tid & 15;
    const int s = blockIdx.x * 16 + seq;
    const int b = s / NN, n = s % NN;
    const size_t ebase = ((size_t)b * (TT * NN) + n) * HIDF + part * 4;
    const int u0 = part * 4;
    const size_t xbase = ((size_t)b * (TT * NN) + n) * HIDF + u0;

    union { short s8[8]; bf16x8 v; } bf[2][2][4];
    {
        const int colb = wv * 64 + c;
        #pragma unroll
        for (int m = 0; m < 2; ++m) {
            const float* W = m ? Whh : Wih;
            #pragma unroll
            for (int kc = 0; kc < 2; ++kc)
                #pragma unroll
                for (int nt = 0; nt < 4; ++nt)
                    #pragma unroll
                    for (int j = 0; j < 8; ++j)
                        bf[m][kc][nt].s8[j] = bf16s_rne(W[(size_t)(kc * 32 + q * 8 + j) * 256 + colb + nt * 16]);
        }
    }
    float4 bi, bfo, bg, bo;
    {
        float* bp[4] = {&bi.x, &bfo.x, &bg.x, &bo.x};
        #pragma unroll
        for (int gsel = 0; gsel < 4; ++gsel)
            #pragma unroll
            for (int r = 0; r < 4; ++r)
                bp[gsel][r] = bih[gsel * 64 + u0 + r] + bhh[gsel * 64 + u0 + r];
    }
    for (int i = tid; i < 16 * 72 / 2; i += 256) ((unsigned*)hbuf)[i] = 0u;
    {
        float4 e0 = *(const float4*)&emb[ebase];
        uint2 pk; pk.x = bf16pk_rne(e0.x, e0.y); pk.y = bf16pk_rne(e0.z, e0.w);
        *(uint2*)&embt[0][seq * 72 + part * 4] = pk;
    }
    float cst[4] = {0.f, 0.f, 0.f, 0.f};
    __syncthreads();

    for (int t = 0; t < TT; ++t) {
        float4 pre;
        if (t + 1 < TT) pre = *(const float4*)&emb[ebase + (size_t)(t + 1) * (NN * HIDF)];
        const short* et = &embt[t & 1][0];
        bf16x8 a_e0 = *(const bf16x8*)&et[c * 72 + q * 8];
        bf16x8 a_e1 = *(const bf16x8*)&et[c * 72 + 32 + q * 8];
        bf16x8 a_h0 = *(const bf16x8*)&hbuf[c * 72 + q * 8];
        bf16x8 a_h1 = *(const bf16x8*)&hbuf[c * 72 + 32 + q * 8];
        f32x4 acc[4];
        #pragma unroll
        for (int nt = 0; nt < 4; ++nt) {
            f32x4 a = {0.f, 0.f, 0.f, 0.f};
            a = __builtin_amdgcn_mfma_f32_16x16x32_bf16(a_e0, bf[0][0][nt].v, a, 0, 0, 0);
            a = __builtin_amdgcn_mfma_f32_16x16x32_bf16(a_e1, bf[0][1][nt].v, a, 0, 0, 0);
            a = __builtin_amdgcn_mfma_f32_16x16x32_bf16(a_h0, bf[1][0][nt].v, a, 0, 0, 0);
            a = __builtin_amdgcn_mfma_f32_16x16x32_bf16(a_h1, bf[1][1][nt].v, a, 0, 0, 0);
            acc[nt] = a;
        }
        #pragma unroll
        for (int nt = 0; nt < 4; ++nt)
            #pragma unroll
            for (int r = 0; r < 4; ++r)
                gbuf[(q * 4 + r) * GSTRIDE + wv * 64 + nt * 16 + c] = acc[nt][r];
        __syncthreads();
        if (t + 1 < TT) {
            uint2 pk; pk.x = bf16pk_rne(pre.x, pre.y); pk.y = bf16pk_rne(pre.z, pre.w);
            *(uint2*)&embt[(t + 1) & 1][seq * 72 + part * 4] = pk;
        }
        float4 gi = *(const float4*)&gbuf[seq * GSTRIDE + u0];
        float4 gf = *(const float4*)&gbuf[seq * GSTRIDE + 64 + u0];
        float4 gg = *(const float4*)&gbuf[seq * GSTRIDE + 128 + u0];
        float4 go = *(const float4*)&gbuf[seq * GSTRIDE + 192 + u0];
        float hv[4];
        {
            float gir[4] = {gi.x + bi.x, gi.y + bi.y, gi.z + bi.z, gi.w + bi.w};
            float gfr[4] = {gf.x + bfo.x, gf.y + bfo.y, gf.z + bfo.z, gf.w + bfo.w};
            float ggr[4] = {gg.x + bg.x, gg.y + bg.y, gg.z + bg.z, gg.w + bg.w};
            float gor[4] = {go.x + bo.x, go.y + bo.y, go.z + bo.z, go.w + bo.w};
            #pragma unroll
            for (int r = 0; r < 4; ++r) {
                cst[r] = sigmf(gfr[r]) * cst[r] + sigmf(gir[r]) * tanh_fast(ggr[r]);
                hv[r] = sigmf(gor[r]) * tanh_fast(cst[r]);
            }
        }
        uint2 hpk; hpk.x = bf16pk_rne(hv[0], hv[1]); hpk.y = bf16pk_rne(hv[2], hv[3]);
        *(uint2*)&hbuf[seq * 72 + u0] = hpk;
        float4 xo; xo.x = hv[0]; xo.y = hv[1]; xo.z = hv[2]; xo.w = hv[3];
        *(float4*)&xenc[xbase + (size_t)t * (NN * HIDF)] = xo;
        __syncthreads();
    }
}

// ---------------------------------------------------------------- fused GAT layer (VALU)
// BT = block threads (512 raises waves/CU; grid is only 3.1 blocks/CU).
// OUTMODE 0: concat heads + elu(+bias); 1: single head + bias; 2: +bias then * mgate
template <int BT, int FIN1, int FIN2, int H, int FOUT, int SPLIT, int OUTMODE>
__launch_bounds__(BT)
__global__ void gat_kernel(const float* __restrict__ x1, const float* __restrict__ x2,
                           const float* __restrict__ w, const float* __restrict__ asrc,
                           const float* __restrict__ adst, const float* __restrict__ bias,
                           const unsigned long long* __restrict__ adjmask,
                           const float* __restrict__ mgate, float* __restrict__ out) {
    constexpr int FIN = FIN1 + FIN2;
    constexpr int HF = H * FOUT;
    constexpr int NPT = BT / HF;                     // rows in flight
    constexpr int ROWS = (NN + NPT - 1) / NPT;
    constexpr int SB = NN * (FIN > HF ? FIN : HF);
    __shared__ __align__(16) float sbuf[SB];
    __shared__ __align__(16) float ses[H * NN];
    __shared__ __align__(16) float sed[H * NN];
    __shared__ unsigned long long smask[2 * NN];
    int g = blockIdx.x;
    int tid = threadIdx.x;

    for (int i = tid; i < NN * FIN1; i += BT) {
        int n = i / FIN1, k = i % FIN1;
        sbuf[n * FIN + k] = x1[((size_t)g * NN + n) * FIN1 + k];
    }
    if constexpr (FIN2 > 0) {
        for (int i = tid; i < NN * FIN2; i += BT) {
            int n = i / FIN2, k = i % FIN2;
            sbuf[n * FIN + FIN1 + k] = x2[(size_t)g * FIN2 + k];
        }
    }
    if (tid < 2 * NN) smask[tid] = adjmask[tid];
    __syncthreads();

    const int ho = tid % HF;
    const int h = ho / FOUT, o = ho % FOUT;
    const int n0 = tid / HF;
    float racc[ROWS];
    {
        float wcol[FIN];
        #pragma unroll
        for (int k = 0; k < FIN; ++k) wcol[k] = w[(h * FIN + k) * FOUT + o];
        const float as = asrc[ho], ad = adst[ho];
        #pragma unroll
        for (int r = 0; r < ROWS; ++r) {
            int n = n0 + r * NPT;
            float acc = 0.f;
            if (ROWS * NPT == NN || n < NN) {
                const float4* row = (const float4*)&sbuf[n * FIN];
                #pragma unroll
                for (int k4 = 0; k4 < FIN / 4; ++k4) {
                    float4 xv = row[k4];
                    acc += xv.x * wcol[4 * k4] + xv.y * wcol[4 * k4 + 1]
                         + xv.z * wcol[4 * k4 + 2] + xv.w * wcol[4 * k4 + 3];
                }
            }
            racc[r] = acc;
            float vs = acc * as, vd = acc * ad;
            #pragma unroll
            for (int off = FOUT / 2; off >= 1; off >>= 1) {
                vs += __shfl_xor(vs, off, 64);
                vd += __shfl_xor(vd, off, 64);
            }
            if (o == 0 && (ROWS * NPT == NN || n < NN)) {
                ses[h * NN + n] = vs; sed[h * NN + n] = vd;
            }
        }
    }
    __syncthreads();
    #pragma unroll
    for (int r = 0; r < ROWS; ++r) {
        int n = n0 + r * NPT;
        if (ROWS * NPT == NN || n < NN) sbuf[n * HF + ho] = racc[r];
    }
    __syncthreads();

    constexpr int FT = FOUT / SPLIT;
    constexpr int ITEMS = H * NN * SPLIT;
    for (int idx = tid; idx < ITEMS; idx += BT) {
        int h2 = idx / (NN * SPLIT);
        int rem = idx % (NN * SPLIT);
        int n = rem / SPLIT;
        int os = (rem % SPLIT) * FT;
        unsigned long long m0 = smask[2 * n], m1 = smask[2 * n + 1];
        float esn = ses[h2 * NN + n];
        float denom = 0.f;
        float acc[FT];
        #pragma unroll
        for (int qq = 0; qq < FT; ++qq) acc[qq] = 0.f;
        const float4* sed4 = (const float4*)&sed[h2 * NN];
        #pragma unroll 2
        for (int g4 = 0; g4 < NN / 4; ++g4) {
            float4 ev = sed4[g4];
            unsigned int bits = (g4 < 16) ? (unsigned int)(m0 >> (4 * g4))
                                          : (unsigned int)(m1 >> (4 * g4 - 64));
            float e0 = esn + ev.x; e0 = (e0 > 0.f) ? e0 : 0.2f * e0;
            float e1 = esn + ev.y; e1 = (e1 > 0.f) ? e1 : 0.2f * e1;
            float e2 = esn + ev.z; e2 = (e2 > 0.f) ? e2 : 0.2f * e2;
            float e3 = esn + ev.w; e3 = (e3 > 0.f) ? e3 : 0.2f * e3;
            float p0 = (bits & 1u) ? __expf(e0) : 0.f;
            float p1 = (bits & 2u) ? __expf(e1) : 0.f;
            float p2 = (bits & 4u) ? __expf(e2) : 0.f;
            float p3 = (bits & 8u) ? __expf(e3) : 0.f;
            denom += (p0 + p1) + (p2 + p3);
            const float* r0 = &sbuf[(4 * g4 + 0) * HF + h2 * FOUT + os];
            const float* r1 = &sbuf[(4 * g4 + 1) * HF + h2 * FOUT + os];
            const float* r2 = &sbuf[(4 * g4 + 2) * HF + h2 * FOUT + os];
            const float* r3 = &sbuf[(4 * g4 + 3) * HF + h2 * FOUT + os];
            #pragma unroll
            for (int q4 = 0; q4 < FT / 4; ++q4) {
                float4 v0 = ((const float4*)r0)[q4];
                float4 v1 = ((const float4*)r1)[q4];
                float4 v2 = ((const float4*)r2)[q4];
                float4 v3 = ((const float4*)r3)[q4];
                acc[4 * q4 + 0] += p0 * v0.x + p1 * v1.x + p2 * v2.x + p3 * v3.x;
                acc[4 * q4 + 1] += p0 * v0.y + p1 * v1.y + p2 * v2.y + p3 * v3.y;
                acc[4 * q4 + 2] += p0 * v0.z + p1 * v1.z + p2 * v2.z + p3 * v3.z;
                acc[4 * q4 + 3] += p0 * v0.w + p1 * v1.w + p2 * v2.w + p3 * v3.w;
            }
        }
        float inv = 1.f / denom;
        if constexpr (OUTMODE == 0) {
            float4* op = (float4*)&out[((size_t)g * NN + n) * HF + h2 * FOUT + os];
            #pragma unroll
            for (int q4 = 0; q4 < FT / 4; ++q4) {
                float4 v;
                float a0 = acc[4 * q4 + 0] * inv + bias[h2 * FOUT + os + 4 * q4 + 0];
                float a1 = acc[4 * q4 + 1] * inv + bias[h2 * FOUT + os + 4 * q4 + 1];
                float a2 = acc[4 * q4 + 2] * inv + bias[h2 * FOUT + os + 4 * q4 + 2];
                float a3 = acc[4 * q4 + 3] * inv + bias[h2 * FOUT + os + 4 * q4 + 3];
                v.x = (a0 > 0.f) ? a0 : (__expf(a0) - 1.f);
                v.y = (a1 > 0.f) ? a1 : (__expf(a1) - 1.f);
                v.z = (a2 > 0.f) ? a2 : (__expf(a2) - 1.f);
                v.w = (a3 > 0.f) ? a3 : (__expf(a3) - 1.f);
                op[q4] = v;
            }
        } else if constexpr (OUTMODE == 1) {
            float4* op = (float4*)&out[((size_t)g * NN + n) * FOUT + os];
            #pragma unroll
            for (int q4 = 0; q4 < FT / 4; ++q4) {
                float4 v;
                v.x = acc[4 * q4 + 0] * inv + bias[os + 4 * q4 + 0];
                v.y = acc[4 * q4 + 1] * inv + bias[os + 4 * q4 + 1];
                v.z = acc[4 * q4 + 2] * inv + bias[os + 4 * q4 + 2];
                v.w = acc[4 * q4 + 3] * inv + bias[os + 4 * q4 + 3];
                op[q4] = v;
            }
        } else {
            size_t base = ((size_t)g * NN + n) * FOUT + os;
            float4* op = (float4*)&out[base];
            const float4* mp = (const float4*)&mgate[base];
            #pragma unroll
            for (int q4 = 0; q4 < FT / 4; ++q4) {
                float4 mv = mp[q4];
                float4 v;
                v.x = (acc[4 * q4 + 0] * inv + bias[os + 4 * q4 + 0]) * mv.x;
                v.y = (acc[4 * q4 + 1] * inv + bias[os + 4 * q4 + 1]) * mv.y;
                v.z = (acc[4 * q4 + 2] * inv + bias[os + 4 * q4 + 2]) * mv.z;
                v.w = (acc[4 * q4 + 3] * inv + bias[os + 4 * q4 + 3]) * mv.w;
                op[q4] = v;
            }
        }
    }
}

// ---------------------------------------------------------------- pool + reparameterize
__global__ void pool_kernel(const float* __restrict__ g2, const float* __restrict__ eps,
                            float* __restrict__ z, float* __restrict__ dout) {
    int g = blockIdx.x;
    int c = threadIdx.x;
    __shared__ float s[2 * LATF];
    if (c < 2 * LATF) {
        float sum = 0.f;
        for (int n = 0; n < NN; ++n) sum += g2[((size_t)g * NN + n) * (2 * LATF) + c];
        s[c] = sum * (1.f / NN);
    }
    __syncthreads();
    if (c < LATF) {
        float mu = s[c], lv = s[LATF + c];
        dout[640000 + (size_t)g * LATF + c] = mu;
        dout[652800 + (size_t)g * LATF + c] = lv;
        z[(size_t)g * LATF + c] = mu + eps[(size_t)g * LATF + c] * __expf(0.5f * lv);
    }
}

// ---------------------------------------------------------------- launch
extern "C" void kernel_launch(void* const* d_in, const int* in_sizes, int n_in,
                              void* d_out, int out_size, void* d_ws, size_t ws_size,
                              hipStream_t stream) {
    const float* o     = (const float*)d_in[0];
    const float* aprev = (const float*)d_in[1];
    const float* mk    = (const float*)d_in[2];
    const float* eps   = (const float*)d_in[3];
    const int*   adj   = (const int*)d_in[4];
    const float* Wobs  = (const float*)d_in[5];
    const float* bobs  = (const float*)d_in[6];
    const float* Wpa   = (const float*)d_in[7];
    const float* bpa   = (const float*)d_in[8];
    const float* Wmk   = (const float*)d_in[9];
    const float* bmk   = (const float*)d_in[10];
    const float* idemb = (const float*)d_in[11];
    const float* lWih  = (const float*)d_in[12];
    const float* lWhh  = (const float*)d_in[13];
    const float* lbih  = (const float*)d_in[14];
    const float* lbhh  = (const float*)d_in[15];
    const float* e1w = (const float*)d_in[16]; const float* e1s = (const float*)d_in[17];
    const float* e1d = (const float*)d_in[18]; const float* e1b = (const float*)d_in[19];
    const float* e2w = (const float*)d_in[20]; const float* e2s = (const float*)d_in[21];
    const float* e2d = (const float*)d_in[22]; const float* e2b = (const float*)d_in[23];
    const float* d1w = (const float*)d_in[24]; const float* d1s = (const float*)d_in[25];
    const float* d1d = (const float*)d_in[26]; const float* d1b = (const float*)d_in[27];
    const float* d2w = (const float*)d_in[28]; const float* d2s = (const float*)d_in[29];
    const float* d2d = (const float*)d_in[30]; const float* d2b = (const float*)d_in[31];
    const float* d3w = (const float*)d_in[32]; const float* d3s = (const float*)d_in[33];
    const float* d3d = (const float*)d_in[34]; const float* d3b = (const float*)d_in[35];

    float* ws   = (float*)d_ws;
    float* emb  = ws;
    float* xenc = ws + 5120000;
    float* g1o  = ws + 10240000;
    float* g2o  = ws + 15360000;
    float* z    = ws + 17920000;
    float* d1o  = ws + 18000000;
    float* d2o  = ws + 23200000;
    unsigned long long* amask = (unsigned long long*)(ws + 30720000);
    float* out = (float*)d_out;

    adjmask_kernel<<<1, 128, 0, stream>>>(adj, amask);
    emb_kernel<<<BS * TT * NN, 64, 0, stream>>>(o, aprev, mk, Wobs, bobs, Wpa, bpa,
                                                Wmk, bmk, idemb, emb);
    lstm_mfma_kernel<<<100, 256, 0, stream>>>(emb, lWih, lWhh, lbih, lbhh, xenc);
    gat_kernel<512, 64, 0, 4, 16, 2, 0><<<800, 512, 0, stream>>>(xenc, nullptr, e1w, e1s, e1d, e1b,
                                                                 amask, nullptr, g1o);
    gat_kernel<512, 64, 0, 1, 32, 8, 1><<<800, 512, 0, stream>>>(g1o, nullptr, e2w, e2s, e2d, e2b,
                                                                 amask, nullptr, g2o);
    pool_kernel<<<800, 64, 0, stream>>>(g2o, eps, z, out);
    gat_kernel<512, 64, 16, 4, 16, 2, 0><<<800, 512, 0, stream>>>(emb, z, d1w, d1s, d1d, d1b,
                                                                  amask, nullptr, d1o);
    gat_kernel<512, 64, 0, 4, 16, 2, 0><<<800, 512, 0, stream>>>(d1o, nullptr, d2w, d2s, d2d, d2b,
                                                                 amask, nullptr, d2o);
    gat_kernel<256, 64, 0, 1, 8, 2, 2><<<800, 256, 0, stream>>>(d2o, nullptr, d3w, d3s, d3d, d3b,
                                                                amask, mk, out);
}

// Round 10
// 526.260 us; speedup vs baseline: 1.0701x; 1.0701x over previous
//
#include <hip/hip_runtime.h>

#define BS  16
#define TT  50
#define NN  100
#define OBSF 40
#define ACTF 8
#define HIDF 64
#define LATF 16

typedef __attribute__((ext_vector_type(8))) short bf16x8;
typedef __attribute__((ext_vector_type(4))) float f32x4;
typedef __fp16 f16x2 __attribute__((ext_vector_type(2)));

__device__ __forceinline__ float sigmf(float x) { return 1.f / (1.f + __expf(-x)); }
__device__ __forceinline__ float tanh_fast(float x) { return 1.f - 2.f / (__expf(2.f * x) + 1.f); }
__device__ __forceinline__ short bf16s_rne(float a) {
    unsigned u = __float_as_uint(a); u += 0x7fffu + ((u >> 16) & 1u);
    return (short)(u >> 16);
}
__device__ __forceinline__ unsigned bf16pk_rne(float a, float b) {
    unsigned ua = __float_as_uint(a); ua += 0x7fffu + ((ua >> 16) & 1u);
    unsigned ub = __float_as_uint(b); ub += 0x7fffu + ((ub >> 16) & 1u);
    return (ua >> 16) | (ub & 0xffff0000u);
}

// ---------------------------------------------------------------- adj bitmask
__global__ void adjmask_kernel(const int* __restrict__ adj, unsigned long long* __restrict__ mask) {
    int n = threadIdx.x;
    if (n < NN) {
        unsigned long long w0 = 0ull, w1 = 0ull;
        for (int m = 0; m < 64; ++m)  if (adj[n * NN + m] > 0) w0 |= (1ull << m);
        for (int m = 64; m < NN; ++m) if (adj[n * NN + m] > 0) w1 |= (1ull << (m - 64));
        mask[2 * n] = w0; mask[2 * n + 1] = w1;
    }
}

// ---------------------------------------------------------------- embedding
__global__ void emb_kernel(const float* __restrict__ o, const float* __restrict__ ap,
                           const float* __restrict__ mk,
                           const float* __restrict__ Wobs, const float* __restrict__ bobs,
                           const float* __restrict__ Wpa, const float* __restrict__ bpa,
                           const float* __restrict__ Wmk, const float* __restrict__ bmk,
                           const float* __restrict__ idemb, float* __restrict__ emb) {
    int g = blockIdx.x;               // (b*T+t)*N + n
    int n = g % NN;
    int j = threadIdx.x;              // 0..63
    __shared__ float so[OBSF], sa[ACTF], sm[ACTF];
    if (j < OBSF) so[j] = o[(size_t)g * OBSF + j];
    if (j >= 40 && j < 48) sa[j - 40] = ap[(size_t)g * ACTF + (j - 40)];
    if (j >= 48 && j < 56) sm[j - 48] = mk[(size_t)g * ACTF + (j - 48)];
    __syncthreads();
    float acc = bobs[j] + bpa[j] + bmk[j] + idemb[n * HIDF + j];
    #pragma unroll
    for (int k = 0; k < OBSF; ++k) acc += so[k] * Wobs[k * HIDF + j];
    #pragma unroll
    for (int k = 0; k < ACTF; ++k) acc += sa[k] * Wpa[k * HIDF + j] + sm[k] * Wmk[k * HIDF + j];
    emb[(size_t)g * HIDF + j] = acc;
}

// ---------------------------------------------------------------- MFMA LSTM (round-7, kept)
__launch_bounds__(256)
__global__ void lstm_mfma_kernel(const float* __restrict__ emb,
                                 const float* __restrict__ Wih, const float* __restrict__ Whh,
                                 const float* __restrict__ bih, const float* __restrict__ bhh,
                                 float* __restrict__ xenc) {
    constexpr int GSTRIDE = 260;
    __shared__ __align__(16) float gbuf[16 * GSTRIDE];
    __shared__ __align__(16) short embt[2][16 * 72];
    __shared__ __align__(16) short hbuf[16 * 72];

    const int tid = threadIdx.x;
    const int wv = tid >> 6, lane = tid & 63, q = lane >> 4, c = lane & 15;

    const int seq = tid >> 4;
    const int part = tid & 15;
    const int s = blockIdx.x * 16 + seq;
    const int b = s / NN, n = s % NN;
    const size_t ebase = ((size_t)b * (TT * NN) + n) * HIDF + part * 4;
    const int u0 = part * 4;
    const size_t xbase = ((size_t)b * (TT * NN) + n) * HIDF + u0;

    union { short s8[8]; bf16x8 v; } bf[2][2][4];
    {
        const int colb = wv * 64 + c;
        #pragma unroll
        for (int m = 0; m < 2; ++m) {
            const float* W = m ? Whh : Wih;
            #pragma unroll
            for (int kc = 0; kc < 2; ++kc)
                #pragma unroll
                for (int nt = 0; nt < 4; ++nt)
                    #pragma unroll
                    for (int j = 0; j < 8; ++j)
                        bf[m][kc][nt].s8[j] = bf16s_rne(W[(size_t)(kc * 32 + q * 8 + j) * 256 + colb + nt * 16]);
        }
    }
    float4 bi, bfo, bg, bo;
    {
        float* bp[4] = {&bi.x, &bfo.x, &bg.x, &bo.x};
        #pragma unroll
        for (int gsel = 0; gsel < 4; ++gsel)
            #pragma unroll
            for (int r = 0; r < 4; ++r)
                bp[gsel][r] = bih[gsel * 64 + u0 + r] + bhh[gsel * 64 + u0 + r];
    }
    for (int i = tid; i < 16 * 72 / 2; i += 256) ((unsigned*)hbuf)[i] = 0u;
    {
        float4 e0 = *(const float4*)&emb[ebase];
        uint2 pk; pk.x = bf16pk_rne(e0.x, e0.y); pk.y = bf16pk_rne(e0.z, e0.w);
        *(uint2*)&embt[0][seq * 72 + part * 4] = pk;
    }
    float cst[4] = {0.f, 0.f, 0.f, 0.f};
    __syncthreads();

    for (int t = 0; t < TT; ++t) {
        float4 pre;
        if (t + 1 < TT) pre = *(const float4*)&emb[ebase + (size_t)(t + 1) * (NN * HIDF)];
        const short* et = &embt[t & 1][0];
        bf16x8 a_e0 = *(const bf16x8*)&et[c * 72 + q * 8];
        bf16x8 a_e1 = *(const bf16x8*)&et[c * 72 + 32 + q * 8];
        bf16x8 a_h0 = *(const bf16x8*)&hbuf[c * 72 + q * 8];
        bf16x8 a_h1 = *(const bf16x8*)&hbuf[c * 72 + 32 + q * 8];
        f32x4 acc[4];
        #pragma unroll
        for (int nt = 0; nt < 4; ++nt) {
            f32x4 a = {0.f, 0.f, 0.f, 0.f};
            a = __builtin_amdgcn_mfma_f32_16x16x32_bf16(a_e0, bf[0][0][nt].v, a, 0, 0, 0);
            a = __builtin_amdgcn_mfma_f32_16x16x32_bf16(a_e1, bf[0][1][nt].v, a, 0, 0, 0);
            a = __builtin_amdgcn_mfma_f32_16x16x32_bf16(a_h0, bf[1][0][nt].v, a, 0, 0, 0);
            a = __builtin_amdgcn_mfma_f32_16x16x32_bf16(a_h1, bf[1][1][nt].v, a, 0, 0, 0);
            acc[nt] = a;
        }
        #pragma unroll
        for (int nt = 0; nt < 4; ++nt)
            #pragma unroll
            for (int r = 0; r < 4; ++r)
                gbuf[(q * 4 + r) * GSTRIDE + wv * 64 + nt * 16 + c] = acc[nt][r];
        __syncthreads();
        if (t + 1 < TT) {
            uint2 pk; pk.x = bf16pk_rne(pre.x, pre.y); pk.y = bf16pk_rne(pre.z, pre.w);
            *(uint2*)&embt[(t + 1) & 1][seq * 72 + part * 4] = pk;
        }
        float4 gi = *(const float4*)&gbuf[seq * GSTRIDE + u0];
        float4 gf = *(const float4*)&gbuf[seq * GSTRIDE + 64 + u0];
        float4 gg = *(const float4*)&gbuf[seq * GSTRIDE + 128 + u0];
        float4 go = *(const float4*)&gbuf[seq * GSTRIDE + 192 + u0];
        float hv[4];
        {
            float gir[4] = {gi.x + bi.x, gi.y + bi.y, gi.z + bi.z, gi.w + bi.w};
            float gfr[4] = {gf.x + bfo.x, gf.y + bfo.y, gf.z + bfo.z, gf.w + bfo.w};
            float ggr[4] = {gg.x + bg.x, gg.y + bg.y, gg.z + bg.z, gg.w + bg.w};
            float gor[4] = {go.x + bo.x, go.y + bo.y, go.z + bo.z, go.w + bo.w};
            #pragma unroll
            for (int r = 0; r < 4; ++r) {
                cst[r] = sigmf(gfr[r]) * cst[r] + sigmf(gir[r]) * tanh_fast(ggr[r]);
                hv[r] = sigmf(gor[r]) * tanh_fast(cst[r]);
            }
        }
        uint2 hpk; hpk.x = bf16pk_rne(hv[0], hv[1]); hpk.y = bf16pk_rne(hv[2], hv[3]);
        *(uint2*)&hbuf[seq * 72 + u0] = hpk;
        float4 xo; xo.x = hv[0]; xo.y = hv[1]; xo.z = hv[2]; xo.w = hv[3];
        *(float4*)&xenc[xbase + (size_t)t * (NN * HIDF)] = xo;
        __syncthreads();
    }
}

// ---------------------------------------------------------------- fused GAT layer
// Phase 2 aggregation via f16 fdot2 (2 MACs/inst) against a transposed f16
// h-tile sh16[o][m] (stride 112, cols >=100 zeroed — 0*garbage=NaN hazard).
// FIN2>0: x2 (z) is per-graph constant -> zdot folded once per thread, not
// stored per node. OUTMODE 0: concat+elu; 1: +bias; 2: +bias then * mgate.
template <int FIN1, int FIN2, int H, int FOUT, int SPLIT, int OUTMODE>
__launch_bounds__(256)
__global__ void gat_kernel(const float* __restrict__ x1, const float* __restrict__ x2,
                           const float* __restrict__ w, const float* __restrict__ asrc,
                           const float* __restrict__ adst, const float* __restrict__ bias,
                           const unsigned long long* __restrict__ adjmask,
                           const float* __restrict__ mgate, float* __restrict__ out) {
    constexpr int FIN = FIN1 + FIN2;
    constexpr int HF = H * FOUT;
    constexpr int NPT = 256 / HF;
    constexpr int ROWS = (NN + NPT - 1) / NPT;
    constexpr int SXB = NN * FIN1 * 4;               // x-tile bytes (fp32)
    constexpr int SHB = HF * 112 * 2;                // h-tile bytes (f16, transposed)
    constexpr int R1 = (SXB > SHB) ? SXB : SHB;
    __shared__ __align__(16) char smem[R1];
    float* sx = (float*)smem;                        // phase 1
    __fp16* sh16 = (__fp16*)smem;                    // phase 2 alias
    __shared__ float sz[FIN2 > 0 ? FIN2 : 1];
    __shared__ __align__(16) float ses[H * 112];
    __shared__ __align__(16) float sed[H * 112];
    __shared__ unsigned long long smask[2 * NN];
    int g = blockIdx.x;
    int tid = threadIdx.x;

    for (int i = tid; i < NN * FIN1; i += 256) {
        int n = i / FIN1, k = i % FIN1;
        sx[n * FIN1 + k] = x1[((size_t)g * NN + n) * FIN1 + k];
    }
    if constexpr (FIN2 > 0) {
        if (tid < FIN2) sz[tid] = x2[(size_t)g * FIN2 + tid];
    }
    if (tid < 2 * NN) smask[tid] = adjmask[tid];
    __syncthreads();

    // ---- phase 1: h = x @ w (+ zdot), e_src/e_dst via shfl over FOUT lanes
    const int ho = tid % HF;
    const int h = ho / FOUT, o = ho % FOUT;
    const int n0 = tid / HF;
    float racc[ROWS];
    {
        float wcol[FIN];
        #pragma unroll
        for (int k = 0; k < FIN; ++k) wcol[k] = w[((size_t)h * FIN + k) * FOUT + o];
        float zdot = 0.f;
        if constexpr (FIN2 > 0) {
            #pragma unroll
            for (int k = 0; k < FIN2; ++k) zdot += sz[k] * wcol[FIN1 + k];
        }
        const float as = asrc[ho], ad = adst[ho];
        #pragma unroll
        for (int r = 0; r < ROWS; ++r) {
            int n = n0 + r * NPT;
            float acc = zdot;
            if (ROWS * NPT == NN || n < NN) {
                const float4* row = (const float4*)&sx[n * FIN1];
                #pragma unroll
                for (int k4 = 0; k4 < FIN1 / 4; ++k4) {
                    float4 xv = row[k4];
                    acc += xv.x * wcol[4 * k4] + xv.y * wcol[4 * k4 + 1]
                         + xv.z * wcol[4 * k4 + 2] + xv.w * wcol[4 * k4 + 3];
                }
            }
            racc[r] = acc;
            float vs = acc * as, vd = acc * ad;
            #pragma unroll
            for (int off = FOUT / 2; off >= 1; off >>= 1) {
                vs += __shfl_xor(vs, off, 64);
                vd += __shfl_xor(vd, off, 64);
            }
            if (o == 0 && (ROWS * NPT == NN || n < NN)) {
                ses[h * 112 + n] = vs; sed[h * 112 + n] = vd;
            }
        }
    }
    __syncthreads();   // sx dead; region becomes sh16
    #pragma unroll
    for (int r = 0; r < ROWS; ++r) {
        int n = n0 + r * NPT;
        if (ROWS * NPT == NN || n < NN) sh16[ho * 112 + n] = (__fp16)racc[r];
    }
    for (int i = tid; i < HF * 12; i += 256)
        sh16[(i / 12) * 112 + 100 + (i % 12)] = (__fp16)0.f;
    for (int i = tid; i < H * 12; i += 256)
        sed[(i / 12) * 112 + 100 + (i % 12)] = 0.f;
    __syncthreads();

    // ---- phase 2: single-pass masked softmax + fdot2 aggregation (8 m / group)
    constexpr int FT = FOUT / SPLIT;
    constexpr int ITEMS = H * NN * SPLIT;
    for (int idx = tid; idx < ITEMS; idx += 256) {
        int h2 = idx / (NN * SPLIT);
        int rem = idx % (NN * SPLIT);
        int n = rem / SPLIT;
        int os = (rem % SPLIT) * FT;
        unsigned long long m0 = smask[2 * n], m1 = smask[2 * n + 1];
        float esn = ses[h2 * 112 + n];
        float denom = 0.f;
        float acc[FT];
        #pragma unroll
        for (int qq = 0; qq < FT; ++qq) acc[qq] = 0.f;
        const float4* sedf4 = (const float4*)&sed[h2 * 112];
        const __fp16* hb = &sh16[(h2 * FOUT + os) * 112];
        #pragma unroll 2
        for (int gg = 0; gg < 13; ++gg) {
            unsigned mb = (gg < 8) ? (unsigned)(m0 >> (8 * gg)) & 0xffu
                                   : (unsigned)(m1 >> (8 * (gg - 8))) & 0xffu;
            float4 edA = sedf4[2 * gg];
            float4 edB = sedf4[2 * gg + 1];
            float e0 = esn + edA.x; e0 = fmaxf(e0, 0.2f * e0);
            float e1 = esn + edA.y; e1 = fmaxf(e1, 0.2f * e1);
            float e2 = esn + edA.z; e2 = fmaxf(e2, 0.2f * e2);
            float e3 = esn + edA.w; e3 = fmaxf(e3, 0.2f * e3);
            float e4 = esn + edB.x; e4 = fmaxf(e4, 0.2f * e4);
            float e5 = esn + edB.y; e5 = fmaxf(e5, 0.2f * e5);
            float e6 = esn + edB.z; e6 = fmaxf(e6, 0.2f * e6);
            float e7 = esn + edB.w; e7 = fmaxf(e7, 0.2f * e7);
            float p0 = (mb & 1u)   ? __expf(e0) : 0.f;
            float p1 = (mb & 2u)   ? __expf(e1) : 0.f;
            float p2 = (mb & 4u)   ? __expf(e2) : 0.f;
            float p3 = (mb & 8u)   ? __expf(e3) : 0.f;
            float p4 = (mb & 16u)  ? __expf(e4) : 0.f;
            float p5 = (mb & 32u)  ? __expf(e5) : 0.f;
            float p6 = (mb & 64u)  ? __expf(e6) : 0.f;
            float p7 = (mb & 128u) ? __expf(e7) : 0.f;
            denom += ((p0 + p1) + (p2 + p3)) + ((p4 + p5) + (p6 + p7));
            f16x2 q01 = __builtin_amdgcn_cvt_pkrtz(p0, p1);
            f16x2 q23 = __builtin_amdgcn_cvt_pkrtz(p2, p3);
            f16x2 q45 = __builtin_amdgcn_cvt_pkrtz(p4, p5);
            f16x2 q67 = __builtin_amdgcn_cvt_pkrtz(p6, p7);
            #pragma unroll
            for (int oo = 0; oo < FT; ++oo) {
                const f16x2* hp = (const f16x2*)&hb[oo * 112 + gg * 8];
                float a = acc[oo];
                a = __builtin_amdgcn_fdot2(q01, hp[0], a, false);
                a = __builtin_amdgcn_fdot2(q23, hp[1], a, false);
                a = __builtin_amdgcn_fdot2(q45, hp[2], a, false);
                a = __builtin_amdgcn_fdot2(q67, hp[3], a, false);
                acc[oo] = a;
            }
        }
        float inv = 1.f / denom;
        if constexpr (OUTMODE == 0) {
            float4* op = (float4*)&out[((size_t)g * NN + n) * HF + h2 * FOUT + os];
            #pragma unroll
            for (int q4 = 0; q4 < FT / 4; ++q4) {
                float4 v;
                float a0 = acc[4 * q4 + 0] * inv + bias[h2 * FOUT + os + 4 * q4 + 0];
                float a1 = acc[4 * q4 + 1] * inv + bias[h2 * FOUT + os + 4 * q4 + 1];
                float a2 = acc[4 * q4 + 2] * inv + bias[h2 * FOUT + os + 4 * q4 + 2];
                float a3 = acc[4 * q4 + 3] * inv + bias[h2 * FOUT + os + 4 * q4 + 3];
                v.x = (a0 > 0.f) ? a0 : (__expf(a0) - 1.f);
                v.y = (a1 > 0.f) ? a1 : (__expf(a1) - 1.f);
                v.z = (a2 > 0.f) ? a2 : (__expf(a2) - 1.f);
                v.w = (a3 > 0.f) ? a3 : (__expf(a3) - 1.f);
                op[q4] = v;
            }
        } else if constexpr (OUTMODE == 1) {
            float4* op = (float4*)&out[((size_t)g * NN + n) * FOUT + os];
            #pragma unroll
            for (int q4 = 0; q4 < FT / 4; ++q4) {
                float4 v;
                v.x = acc[4 * q4 + 0] * inv + bias[os + 4 * q4 + 0];
                v.y = acc[4 * q4 + 1] * inv + bias[os + 4 * q4 + 1];
                v.z = acc[4 * q4 + 2] * inv + bias[os + 4 * q4 + 2];
                v.w = acc[4 * q4 + 3] * inv + bias[os + 4 * q4 + 3];
                op[q4] = v;
            }
        } else {
            size_t base = ((size_t)g * NN + n) * FOUT + os;
            float4* op = (float4*)&out[base];
            const float4* mp = (const float4*)&mgate[base];
            #pragma unroll
            for (int q4 = 0; q4 < FT / 4; ++q4) {
                float4 mv = mp[q4];
                float4 v;
                v.x = (acc[4 * q4 + 0] * inv + bias[os + 4 * q4 + 0]) * mv.x;
                v.y = (acc[4 * q4 + 1] * inv + bias[os + 4 * q4 + 1]) * mv.y;
                v.z = (acc[4 * q4 + 2] * inv + bias[os + 4 * q4 + 2]) * mv.z;
                v.w = (acc[4 * q4 + 3] * inv + bias[os + 4 * q4 + 3]) * mv.w;
                op[q4] = v;
            }
        }
    }
}

// ---------------------------------------------------------------- pool + reparameterize
__global__ void pool_kernel(const float* __restrict__ g2, const float* __restrict__ eps,
                            float* __restrict__ z, float* __restrict__ dout) {
    int g = blockIdx.x;
    int c = threadIdx.x;
    __shared__ float s[2 * LATF];
    if (c < 2 * LATF) {
        float sum = 0.f;
        for (int n = 0; n < NN; ++n) sum += g2[((size_t)g * NN + n) * (2 * LATF) + c];
        s[c] = sum * (1.f / NN);
    }
    __syncthreads();
    if (c < LATF) {
        float mu = s[c], lv = s[LATF + c];
        dout[640000 + (size_t)g * LATF + c] = mu;
        dout[652800 + (size_t)g * LATF + c] = lv;
        z[(size_t)g * LATF + c] = mu + eps[(size_t)g * LATF + c] * __expf(0.5f * lv);
    }
}

// ---------------------------------------------------------------- launch
extern "C" void kernel_launch(void* const* d_in, const int* in_sizes, int n_in,
                              void* d_out, int out_size, void* d_ws, size_t ws_size,
                              hipStream_t stream) {
    const float* o     = (const float*)d_in[0];
    const float* aprev = (const float*)d_in[1];
    const float* mk    = (const float*)d_in[2];
    const float* eps   = (const float*)d_in[3];
    const int*   adj   = (const int*)d_in[4];
    const float* Wobs  = (const float*)d_in[5];
    const float* bobs  = (const float*)d_in[6];
    const float* Wpa   = (const float*)d_in[7];
    const float* bpa   = (const float*)d_in[8];
    const float* Wmk   = (const float*)d_in[9];
    const float* bmk   = (const float*)d_in[10];
    const float* idemb = (const float*)d_in[11];
    const float* lWih  = (const float*)d_in[12];
    const float* lWhh  = (const float*)d_in[13];
    const float* lbih  = (const float*)d_in[14];
    const float* lbhh  = (const float*)d_in[15];
    const float* e1w = (const float*)d_in[16]; const float* e1s = (const float*)d_in[17];
    const float* e1d = (const float*)d_in[18]; const float* e1b = (const float*)d_in[19];
    const float* e2w = (const float*)d_in[20]; const float* e2s = (const float*)d_in[21];
    const float* e2d = (const float*)d_in[22]; const float* e2b = (const float*)d_in[23];
    const float* d1w = (const float*)d_in[24]; const float* d1s = (const float*)d_in[25];
    const float* d1d = (const float*)d_in[26]; const float* d1b = (const float*)d_in[27];
    const float* d2w = (const float*)d_in[28]; const float* d2s = (const float*)d_in[29];
    const float* d2d = (const float*)d_in[30]; const float* d2b = (const float*)d_in[31];
    const float* d3w = (const float*)d_in[32]; const float* d3s = (const float*)d_in[33];
    const float* d3d = (const float*)d_in[34]; const float* d3b = (const float*)d_in[35];

    float* ws   = (float*)d_ws;
    float* emb  = ws;
    float* xenc = ws + 5120000;
    float* g1o  = ws + 10240000;
    float* g2o  = ws + 15360000;
    float* z    = ws + 17920000;
    float* d1o  = ws + 18000000;
    float* d2o  = ws + 23200000;
    unsigned long long* amask = (unsigned long long*)(ws + 30720000);
    float* out = (float*)d_out;

    adjmask_kernel<<<1, 128, 0, stream>>>(adj, amask);
    emb_kernel<<<BS * TT * NN, 64, 0, stream>>>(o, aprev, mk, Wobs, bobs, Wpa, bpa,
                                                Wmk, bmk, idemb, emb);
    lstm_mfma_kernel<<<100, 256, 0, stream>>>(emb, lWih, lWhh, lbih, lbhh, xenc);
    gat_kernel<64, 0, 4, 16, 1, 0><<<800, 256, 0, stream>>>(xenc, nullptr, e1w, e1s, e1d, e1b,
                                                            amask, nullptr, g1o);
    gat_kernel<64, 0, 1, 32, 4, 1><<<800, 256, 0, stream>>>(g1o, nullptr, e2w, e2s, e2d, e2b,
                                                            amask, nullptr, g2o);
    pool_kernel<<<800, 64, 0, stream>>>(g2o, eps, z, out);
    gat_kernel<64, 16, 4, 16, 1, 0><<<800, 256, 0, stream>>>(emb, z, d1w, d1s, d1d, d1b,
                                                             amask, nullptr, d1o);
    gat_kernel<64, 0, 4, 16, 1, 0><<<800, 256, 0, stream>>>(d1o, nullptr, d2w, d2s, d2d, d2b,
                                                            amask, nullptr, d2o);
    gat_kernel<64, 0, 1, 8, 2, 2><<<800, 256, 0, stream>>>(d2o, nullptr, d3w, d3s, d3d, d3b,
                                                           amask, mk, out);
}

// Round 11
// 480.456 us; speedup vs baseline: 1.1721x; 1.0953x over previous
//
#include <hip/hip_runtime.h>

#define BS  16
#define TT  50
#define NN  100
#define OBSF 40
#define ACTF 8
#define HIDF 64
#define LATF 16

typedef __attribute__((ext_vector_type(8))) short bf16x8;
typedef __attribute__((ext_vector_type(4))) float f32x4;
typedef __fp16 f16x2 __attribute__((ext_vector_type(2)));

__device__ __forceinline__ float sigmf(float x) { return 1.f / (1.f + __expf(-x)); }
__device__ __forceinline__ float tanh_fast(float x) { return 1.f - 2.f / (__expf(2.f * x) + 1.f); }
__device__ __forceinline__ short bf16s_rne(float a) {
    unsigned u = __float_as_uint(a); u += 0x7fffu + ((u >> 16) & 1u);
    return (short)(u >> 16);
}
__device__ __forceinline__ unsigned bf16pk_rne(float a, float b) {
    unsigned ua = __float_as_uint(a); ua += 0x7fffu + ((ua >> 16) & 1u);
    unsigned ub = __float_as_uint(b); ub += 0x7fffu + ((ub >> 16) & 1u);
    return (ua >> 16) | (ub & 0xffff0000u);
}

// ---------------------------------------------------------------- adj bitmask
__global__ void adjmask_kernel(const int* __restrict__ adj, unsigned long long* __restrict__ mask) {
    int n = threadIdx.x;
    if (n < NN) {
        unsigned long long w0 = 0ull, w1 = 0ull;
        for (int m = 0; m < 64; ++m)  if (adj[n * NN + m] > 0) w0 |= (1ull << m);
        for (int m = 64; m < NN; ++m) if (adj[n * NN + m] > 0) w1 |= (1ull << (m - 64));
        mask[2 * n] = w0; mask[2 * n + 1] = w1;
    }
}

// ---------------------------------------------------------------- embedding
__global__ void emb_kernel(const float* __restrict__ o, const float* __restrict__ ap,
                           const float* __restrict__ mk,
                           const float* __restrict__ Wobs, const float* __restrict__ bobs,
                           const float* __restrict__ Wpa, const float* __restrict__ bpa,
                           const float* __restrict__ Wmk, const float* __restrict__ bmk,
                           const float* __restrict__ idemb, float* __restrict__ emb) {
    int g = blockIdx.x;               // (b*T+t)*N + n
    int n = g % NN;
    int j = threadIdx.x;              // 0..63
    __shared__ float so[OBSF], sa[ACTF], sm[ACTF];
    if (j < OBSF) so[j] = o[(size_t)g * OBSF + j];
    if (j >= 40 && j < 48) sa[j - 40] = ap[(size_t)g * ACTF + (j - 40)];
    if (j >= 48 && j < 56) sm[j - 48] = mk[(size_t)g * ACTF + (j - 48)];
    __syncthreads();
    float acc = bobs[j] + bpa[j] + bmk[j] + idemb[n * HIDF + j];
    #pragma unroll
    for (int k = 0; k < OBSF; ++k) acc += so[k] * Wobs[k * HIDF + j];
    #pragma unroll
    for (int k = 0; k < ACTF; ++k) acc += sa[k] * Wpa[k * HIDF + j] + sm[k] * Wmk[k * HIDF + j];
    emb[(size_t)g * HIDF + j] = acc;
}

// ---------------------------------------------------------------- MFMA LSTM (round-7, kept)
__launch_bounds__(256)
__global__ void lstm_mfma_kernel(const float* __restrict__ emb,
                                 const float* __restrict__ Wih, const float* __restrict__ Whh,
                                 const float* __restrict__ bih, const float* __restrict__ bhh,
                                 float* __restrict__ xenc) {
    constexpr int GSTRIDE = 260;
    __shared__ __align__(16) float gbuf[16 * GSTRIDE];
    __shared__ __align__(16) short embt[2][16 * 72];
    __shared__ __align__(16) short hbuf[16 * 72];

    const int tid = threadIdx.x;
    const int wv = tid >> 6, lane = tid & 63, q = lane >> 4, c = lane & 15;

    const int seq = tid >> 4;
    const int part = tid & 15;
    const int s = blockIdx.x * 16 + seq;
    const int b = s / NN, n = s % NN;
    const size_t ebase = ((size_t)b * (TT * NN) + n) * HIDF + part * 4;
    const int u0 = part * 4;
    const size_t xbase = ((size_t)b * (TT * NN) + n) * HIDF + u0;

    union { short s8[8]; bf16x8 v; } bf[2][2][4];
    {
        const int colb = wv * 64 + c;
        #pragma unroll
        for (int m = 0; m < 2; ++m) {
            const float* W = m ? Whh : Wih;
            #pragma unroll
            for (int kc = 0; kc < 2; ++kc)
                #pragma unroll
                for (int nt = 0; nt < 4; ++nt)
                    #pragma unroll
                    for (int j = 0; j < 8; ++j)
                        bf[m][kc][nt].s8[j] = bf16s_rne(W[(size_t)(kc * 32 + q * 8 + j) * 256 + colb + nt * 16]);
        }
    }
    float4 bi, bfo, bg, bo;
    {
        float* bp[4] = {&bi.x, &bfo.x, &bg.x, &bo.x};
        #pragma unroll
        for (int gsel = 0; gsel < 4; ++gsel)
            #pragma unroll
            for (int r = 0; r < 4; ++r)
                bp[gsel][r] = bih[gsel * 64 + u0 + r] + bhh[gsel * 64 + u0 + r];
    }
    for (int i = tid; i < 16 * 72 / 2; i += 256) ((unsigned*)hbuf)[i] = 0u;
    {
        float4 e0 = *(const float4*)&emb[ebase];
        uint2 pk; pk.x = bf16pk_rne(e0.x, e0.y); pk.y = bf16pk_rne(e0.z, e0.w);
        *(uint2*)&embt[0][seq * 72 + part * 4] = pk;
    }
    float cst[4] = {0.f, 0.f, 0.f, 0.f};
    __syncthreads();

    for (int t = 0; t < TT; ++t) {
        float4 pre;
        if (t + 1 < TT) pre = *(const float4*)&emb[ebase + (size_t)(t + 1) * (NN * HIDF)];
        const short* et = &embt[t & 1][0];
        bf16x8 a_e0 = *(const bf16x8*)&et[c * 72 + q * 8];
        bf16x8 a_e1 = *(const bf16x8*)&et[c * 72 + 32 + q * 8];
        bf16x8 a_h0 = *(const bf16x8*)&hbuf[c * 72 + q * 8];
        bf16x8 a_h1 = *(const bf16x8*)&hbuf[c * 72 + 32 + q * 8];
        f32x4 acc[4];
        #pragma unroll
        for (int nt = 0; nt < 4; ++nt) {
            f32x4 a = {0.f, 0.f, 0.f, 0.f};
            a = __builtin_amdgcn_mfma_f32_16x16x32_bf16(a_e0, bf[0][0][nt].v, a, 0, 0, 0);
            a = __builtin_amdgcn_mfma_f32_16x16x32_bf16(a_e1, bf[0][1][nt].v, a, 0, 0, 0);
            a = __builtin_amdgcn_mfma_f32_16x16x32_bf16(a_h0, bf[1][0][nt].v, a, 0, 0, 0);
            a = __builtin_amdgcn_mfma_f32_16x16x32_bf16(a_h1, bf[1][1][nt].v, a, 0, 0, 0);
            acc[nt] = a;
        }
        #pragma unroll
        for (int nt = 0; nt < 4; ++nt)
            #pragma unroll
            for (int r = 0; r < 4; ++r)
                gbuf[(q * 4 + r) * GSTRIDE + wv * 64 + nt * 16 + c] = acc[nt][r];
        __syncthreads();
        if (t + 1 < TT) {
            uint2 pk; pk.x = bf16pk_rne(pre.x, pre.y); pk.y = bf16pk_rne(pre.z, pre.w);
            *(uint2*)&embt[(t + 1) & 1][seq * 72 + part * 4] = pk;
        }
        float4 gi = *(const float4*)&gbuf[seq * GSTRIDE + u0];
        float4 gf = *(const float4*)&gbuf[seq * GSTRIDE + 64 + u0];
        float4 gg = *(const float4*)&gbuf[seq * GSTRIDE + 128 + u0];
        float4 go = *(const float4*)&gbuf[seq * GSTRIDE + 192 + u0];
        float hv[4];
        {
            float gir[4] = {gi.x + bi.x, gi.y + bi.y, gi.z + bi.z, gi.w + bi.w};
            float gfr[4] = {gf.x + bfo.x, gf.y + bfo.y, gf.z + bfo.z, gf.w + bfo.w};
            float ggr[4] = {gg.x + bg.x, gg.y + bg.y, gg.z + bg.z, gg.w + bg.w};
            float gor[4] = {go.x + bo.x, go.y + bo.y, go.z + bo.z, go.w + bo.w};
            #pragma unroll
            for (int r = 0; r < 4; ++r) {
                cst[r] = sigmf(gfr[r]) * cst[r] + sigmf(gir[r]) * tanh_fast(ggr[r]);
                hv[r] = sigmf(gor[r]) * tanh_fast(cst[r]);
            }
        }
        uint2 hpk; hpk.x = bf16pk_rne(hv[0], hv[1]); hpk.y = bf16pk_rne(hv[2], hv[3]);
        *(uint2*)&hbuf[seq * 72 + u0] = hpk;
        float4 xo; xo.x = hv[0]; xo.y = hv[1]; xo.z = hv[2]; xo.w = hv[3];
        *(float4*)&xenc[xbase + (size_t)t * (NN * HIDF)] = xo;
        __syncthreads();
    }
}

// ---------------------------------------------------------------- hybrid MFMA GAT (H=4, FOUT=16, concat+ELU)
// Phase 1: h = x@w via mfma (A-frags shared with a 2nd MFMA chain computing
// es/ed from precomputed wa = w@a_src, wd = w@a_dst — no shuffles).
// FIN2 (z) folded as per-(h,o) zdot and per-head esc/edc constants.
// Phase 2: round-10 fdot2 path on transposed f16 h-tile, stride 120
// (240 B rows: 16B-aligned for b128 merges, period-8 banks — no 16-way conflicts).
template <int FIN2>
__launch_bounds__(256)
__global__ void gat4h_kernel(const float* __restrict__ x1, const float* __restrict__ x2,
                             const float* __restrict__ w, const float* __restrict__ asrc,
                             const float* __restrict__ adst, const float* __restrict__ bias,
                             const unsigned long long* __restrict__ adjmask,
                             float* __restrict__ out) {
    constexpr int FIN = 64 + FIN2;
    __shared__ __align__(16) char regA[112 * 72 * 2];   // sxa [112][72]bf16 ; alias sh16 [64][120]f16
    __shared__ __align__(16) short swb[64 * 72];
    __shared__ __align__(16) short wab[16 * 72];
    __shared__ __align__(16) float ses[4 * 112];
    __shared__ __align__(16) float sed[4 * 112];
    __shared__ float szd[64];
    __shared__ float sesc[4], sedc[4];
    __shared__ unsigned long long smask[2 * NN];
    short* sxa = (short*)regA;
    __fp16* sh16 = (__fp16*)regA;

    const int g = blockIdx.x, tid = threadIdx.x;
    const int wv = tid >> 6, lane = tid & 63, q = lane >> 4, c = lane & 15;

    // ---- stage x (A, bf16, zero-padded rows>=100, k>=64)
    for (int i = tid; i < 112 * 36; i += 256) {
        int n = i / 36, k2 = i % 36, k = 2 * k2;
        float lo = 0.f, hi = 0.f;
        if (n < NN && k < 64) {
            float2 v = *(const float2*)&x1[((size_t)g * NN + n) * 64 + k];
            lo = v.x; hi = v.y;
        }
        ((unsigned*)sxa)[i] = bf16pk_rne(lo, hi);
    }
    // ---- stage w (B layout [col=h*16+o][k])
    for (int i = tid; i < 64 * 36; i += 256) {
        int nc = i / 36, k2 = i % 36, k = 2 * k2;
        int h = nc >> 4, o = nc & 15;
        float lo = 0.f, hi = 0.f;
        if (k < 64) {
            lo = w[((size_t)h * FIN + k) * 16 + o];
            hi = w[((size_t)h * FIN + k + 1) * 16 + o];
        }
        ((unsigned*)swb)[i] = bf16pk_rne(lo, hi);
    }
    // ---- wab: col 2h = (w@asrc)[k], col 2h+1 = (w@adst)[k]; cols 8..15, k>=64 zero
    for (int i = tid; i < 16 * 36; i += 256) {
        int col = i / 36, k2 = i % 36, k = 2 * k2;
        float lo = 0.f, hi = 0.f;
        if (col < 8 && k < 64) {
            int h = col >> 1;
            const float* av = (col & 1) ? adst : asrc;
            float s0 = 0.f, s1 = 0.f;
            #pragma unroll
            for (int o = 0; o < 16; ++o) {
                float a = av[h * 16 + o];
                s0 += w[((size_t)h * FIN + k) * 16 + o] * a;
                s1 += w[((size_t)h * FIN + k + 1) * 16 + o] * a;
            }
            lo = s0; hi = s1;
        }
        ((unsigned*)wab)[i] = bf16pk_rne(lo, hi);
    }
    // ---- zdot per (h,o) from global z (d1 only)
    if constexpr (FIN2 > 0) {
        if (tid < 64) {
            int h = tid >> 4, o = tid & 15;
            float s = 0.f;
            #pragma unroll
            for (int k = 0; k < FIN2; ++k)
                s += x2[(size_t)g * FIN2 + k] * w[((size_t)h * FIN + 64 + k) * 16 + o];
            szd[tid] = s;
        }
    }
    if (tid < 2 * NN) smask[tid] = adjmask[tid];
    __syncthreads();

    // esc/edc = zdot · a{src,dst}
    if constexpr (FIN2 > 0) {
        if (tid < 8) {
            int h = tid >> 1;
            const float* av = (tid & 1) ? adst : asrc;
            float s = 0.f;
            #pragma unroll
            for (int o = 0; o < 16; ++o) s += szd[h * 16 + o] * av[h * 16 + o];
            if (tid & 1) sedc[h] = s; else sesc[h] = s;
        }
    }

    // ---- phase 1: dual MFMA chains sharing A-frags
    f32x4 hc[7], ec[7];
    #pragma unroll
    for (int mt = 0; mt < 7; ++mt) {
        hc[mt] = f32x4{0.f, 0.f, 0.f, 0.f};
        ec[mt] = f32x4{0.f, 0.f, 0.f, 0.f};
    }
    #pragma unroll
    for (int kc = 0; kc < 2; ++kc) {
        bf16x8 bfr = *(const bf16x8*)&swb[(wv * 16 + c) * 72 + kc * 32 + q * 8];
        bf16x8 wfr = *(const bf16x8*)&wab[c * 72 + kc * 32 + q * 8];
        #pragma unroll
        for (int mt = 0; mt < 7; ++mt) {
            bf16x8 afr = *(const bf16x8*)&sxa[(mt * 16 + c) * 72 + kc * 32 + q * 8];
            hc[mt] = __builtin_amdgcn_mfma_f32_16x16x32_bf16(afr, bfr, hc[mt], 0, 0, 0);
            ec[mt] = __builtin_amdgcn_mfma_f32_16x16x32_bf16(afr, wfr, ec[mt], 0, 0, 0);
        }
    }
    float zdv = 0.f, escv = 0.f, edcv = 0.f;
    if constexpr (FIN2 > 0) {
        zdv = szd[wv * 16 + c];
        escv = sesc[wv]; edcv = sedc[wv];
    }
    __syncthreads();   // sxa dead -> sh16

    // ---- writeback: h transposed f16 (stride 120), es/ed from ec cols 2wv/2wv+1
    #pragma unroll
    for (int mt = 0; mt < 7; ++mt) {
        f16x2 p01, p23;
        p01[0] = (__fp16)(hc[mt][0] + zdv); p01[1] = (__fp16)(hc[mt][1] + zdv);
        p23[0] = (__fp16)(hc[mt][2] + zdv); p23[1] = (__fp16)(hc[mt][3] + zdv);
        f16x2* dst = (f16x2*)&sh16[(wv * 16 + c) * 120 + mt * 16 + q * 4];
        dst[0] = p01; dst[1] = p23;
        int nb = wv * 112 + mt * 16 + q * 4;
        if (c == 2 * wv) {
            ses[nb + 0] = ec[mt][0] + escv; ses[nb + 1] = ec[mt][1] + escv;
            ses[nb + 2] = ec[mt][2] + escv; ses[nb + 3] = ec[mt][3] + escv;
        } else if (c == 2 * wv + 1) {
            sed[nb + 0] = ec[mt][0] + edcv; sed[nb + 1] = ec[mt][1] + edcv;
            sed[nb + 2] = ec[mt][2] + edcv; sed[nb + 3] = ec[mt][3] + edcv;
        }
    }
    __syncthreads();

    // ---- phase 2: single-pass masked softmax + fdot2 aggregation
    for (int idx = tid; idx < 4 * NN; idx += 256) {
        int h2 = idx / NN;
        int n = idx % NN;
        unsigned long long m0 = smask[2 * n], m1 = smask[2 * n + 1];
        float esn = ses[h2 * 112 + n];
        float denom = 0.f;
        float acc[16];
        #pragma unroll
        for (int qq = 0; qq < 16; ++qq) acc[qq] = 0.f;
        const float4* sedf4 = (const float4*)&sed[h2 * 112];
        const __fp16* hb = &sh16[(h2 * 16) * 120];
        #pragma unroll 2
        for (int gg = 0; gg < 13; ++gg) {
            unsigned mb = (gg < 8) ? (unsigned)(m0 >> (8 * gg)) & 0xffu
                                   : (unsigned)(m1 >> (8 * (gg - 8))) & 0xffu;
            float4 edA = sedf4[2 * gg];
            float4 edB = sedf4[2 * gg + 1];
            float e0 = esn + edA.x; e0 = fmaxf(e0, 0.2f * e0);
            float e1 = esn + edA.y; e1 = fmaxf(e1, 0.2f * e1);
            float e2 = esn + edA.z; e2 = fmaxf(e2, 0.2f * e2);
            float e3 = esn + edA.w; e3 = fmaxf(e3, 0.2f * e3);
            float e4 = esn + edB.x; e4 = fmaxf(e4, 0.2f * e4);
            float e5 = esn + edB.y; e5 = fmaxf(e5, 0.2f * e5);
            float e6 = esn + edB.z; e6 = fmaxf(e6, 0.2f * e6);
            float e7 = esn + edB.w; e7 = fmaxf(e7, 0.2f * e7);
            float p0 = (mb & 1u)   ? __expf(e0) : 0.f;
            float p1 = (mb & 2u)   ? __expf(e1) : 0.f;
            float p2 = (mb & 4u)   ? __expf(e2) : 0.f;
            float p3 = (mb & 8u)   ? __expf(e3) : 0.f;
            float p4 = (mb & 16u)  ? __expf(e4) : 0.f;
            float p5 = (mb & 32u)  ? __expf(e5) : 0.f;
            float p6 = (mb & 64u)  ? __expf(e6) : 0.f;
            float p7 = (mb & 128u) ? __expf(e7) : 0.f;
            denom += ((p0 + p1) + (p2 + p3)) + ((p4 + p5) + (p6 + p7));
            f16x2 q01 = __builtin_amdgcn_cvt_pkrtz(p0, p1);
            f16x2 q23 = __builtin_amdgcn_cvt_pkrtz(p2, p3);
            f16x2 q45 = __builtin_amdgcn_cvt_pkrtz(p4, p5);
            f16x2 q67 = __builtin_amdgcn_cvt_pkrtz(p6, p7);
            #pragma unroll
            for (int oo = 0; oo < 16; ++oo) {
                const f16x2* hp = (const f16x2*)&hb[oo * 120 + gg * 8];
                float a = acc[oo];
                a = __builtin_amdgcn_fdot2(q01, hp[0], a, false);
                a = __builtin_amdgcn_fdot2(q23, hp[1], a, false);
                a = __builtin_amdgcn_fdot2(q45, hp[2], a, false);
                a = __builtin_amdgcn_fdot2(q67, hp[3], a, false);
                acc[oo] = a;
            }
        }
        float inv = 1.f / denom;
        float4* op = (float4*)&out[((size_t)g * NN + n) * 64 + h2 * 16];
        #pragma unroll
        for (int q4 = 0; q4 < 4; ++q4) {
            float4 v;
            float a0 = acc[4 * q4 + 0] * inv + bias[h2 * 16 + 4 * q4 + 0];
            float a1 = acc[4 * q4 + 1] * inv + bias[h2 * 16 + 4 * q4 + 1];
            float a2 = acc[4 * q4 + 2] * inv + bias[h2 * 16 + 4 * q4 + 2];
            float a3 = acc[4 * q4 + 3] * inv + bias[h2 * 16 + 4 * q4 + 3];
            v.x = (a0 > 0.f) ? a0 : (__expf(a0) - 1.f);
            v.y = (a1 > 0.f) ? a1 : (__expf(a1) - 1.f);
            v.z = (a2 > 0.f) ? a2 : (__expf(a2) - 1.f);
            v.w = (a3 > 0.f) ? a3 : (__expf(a3) - 1.f);
            op[q4] = v;
        }
    }
}

// ---------------------------------------------------------------- VALU GAT (H=1 layers; stride 120)
template <int FIN1, int FIN2, int H, int FOUT, int SPLIT, int OUTMODE>
__launch_bounds__(256)
__global__ void gat_kernel(const float* __restrict__ x1, const float* __restrict__ x2,
                           const float* __restrict__ w, const float* __restrict__ asrc,
                           const float* __restrict__ adst, const float* __restrict__ bias,
                           const unsigned long long* __restrict__ adjmask,
                           const float* __restrict__ mgate, float* __restrict__ out) {
    constexpr int FIN = FIN1 + FIN2;
    constexpr int HF = H * FOUT;
    constexpr int NPT = 256 / HF;
    constexpr int ROWS = (NN + NPT - 1) / NPT;
    constexpr int SXB = NN * FIN1 * 4;
    constexpr int SHB = HF * 120 * 2;
    constexpr int R1 = (SXB > SHB) ? SXB : SHB;
    __shared__ __align__(16) char smem[R1];
    float* sx = (float*)smem;
    __fp16* sh16 = (__fp16*)smem;
    __shared__ float sz[FIN2 > 0 ? FIN2 : 1];
    __shared__ __align__(16) float ses[H * 112];
    __shared__ __align__(16) float sed[H * 112];
    __shared__ unsigned long long smask[2 * NN];
    int g = blockIdx.x;
    int tid = threadIdx.x;

    for (int i = tid; i < NN * FIN1; i += 256) {
        int n = i / FIN1, k = i % FIN1;
        sx[n * FIN1 + k] = x1[((size_t)g * NN + n) * FIN1 + k];
    }
    if constexpr (FIN2 > 0) {
        if (tid < FIN2) sz[tid] = x2[(size_t)g * FIN2 + tid];
    }
    if (tid < 2 * NN) smask[tid] = adjmask[tid];
    __syncthreads();

    const int ho = tid % HF;
    const int h = ho / FOUT, o = ho % FOUT;
    const int n0 = tid / HF;
    float racc[ROWS];
    {
        float wcol[FIN];
        #pragma unroll
        for (int k = 0; k < FIN; ++k) wcol[k] = w[((size_t)h * FIN + k) * FOUT + o];
        float zdot = 0.f;
        if constexpr (FIN2 > 0) {
            #pragma unroll
            for (int k = 0; k < FIN2; ++k) zdot += sz[k] * wcol[FIN1 + k];
        }
        const float as = asrc[ho], ad = adst[ho];
        #pragma unroll
        for (int r = 0; r < ROWS; ++r) {
            int n = n0 + r * NPT;
            float acc = zdot;
            if (ROWS * NPT == NN || n < NN) {
                const float4* row = (const float4*)&sx[n * FIN1];
                #pragma unroll
                for (int k4 = 0; k4 < FIN1 / 4; ++k4) {
                    float4 xv = row[k4];
                    acc += xv.x * wcol[4 * k4] + xv.y * wcol[4 * k4 + 1]
                         + xv.z * wcol[4 * k4 + 2] + xv.w * wcol[4 * k4 + 3];
                }
            }
            racc[r] = acc;
            float vs = acc * as, vd = acc * ad;
            #pragma unroll
            for (int off = FOUT / 2; off >= 1; off >>= 1) {
                vs += __shfl_xor(vs, off, 64);
                vd += __shfl_xor(vd, off, 64);
            }
            if (o == 0 && (ROWS * NPT == NN || n < NN)) {
                ses[h * 112 + n] = vs; sed[h * 112 + n] = vd;
            }
        }
    }
    __syncthreads();
    #pragma unroll
    for (int r = 0; r < ROWS; ++r) {
        int n = n0 + r * NPT;
        if (ROWS * NPT == NN || n < NN) sh16[ho * 120 + n] = (__fp16)racc[r];
    }
    for (int i = tid; i < HF * 20; i += 256)
        sh16[(i / 20) * 120 + 100 + (i % 20)] = (__fp16)0.f;
    for (int i = tid; i < H * 12; i += 256)
        sed[(i / 12) * 112 + 100 + (i % 12)] = 0.f;
    __syncthreads();

    constexpr int FT = FOUT / SPLIT;
    constexpr int ITEMS = H * NN * SPLIT;
    for (int idx = tid; idx < ITEMS; idx += 256) {
        int h2 = idx / (NN * SPLIT);
        int rem = idx % (NN * SPLIT);
        int n = rem / SPLIT;
        int os = (rem % SPLIT) * FT;
        unsigned long long m0 = smask[2 * n], m1 = smask[2 * n + 1];
        float esn = ses[h2 * 112 + n];
        float denom = 0.f;
        float acc[FT];
        #pragma unroll
        for (int qq = 0; qq < FT; ++qq) acc[qq] = 0.f;
        const float4* sedf4 = (const float4*)&sed[h2 * 112];
        const __fp16* hb = &sh16[(h2 * FOUT + os) * 120];
        #pragma unroll 2
        for (int gg = 0; gg < 13; ++gg) {
            unsigned mb = (gg < 8) ? (unsigned)(m0 >> (8 * gg)) & 0xffu
                                   : (unsigned)(m1 >> (8 * (gg - 8))) & 0xffu;
            float4 edA = sedf4[2 * gg];
            float4 edB = sedf4[2 * gg + 1];
            float e0 = esn + edA.x; e0 = fmaxf(e0, 0.2f * e0);
            float e1 = esn + edA.y; e1 = fmaxf(e1, 0.2f * e1);
            float e2 = esn + edA.z; e2 = fmaxf(e2, 0.2f * e2);
            float e3 = esn + edA.w; e3 = fmaxf(e3, 0.2f * e3);
            float e4 = esn + edB.x; e4 = fmaxf(e4, 0.2f * e4);
            float e5 = esn + edB.y; e5 = fmaxf(e5, 0.2f * e5);
            float e6 = esn + edB.z; e6 = fmaxf(e6, 0.2f * e6);
            float e7 = esn + edB.w; e7 = fmaxf(e7, 0.2f * e7);
            float p0 = (mb & 1u)   ? __expf(e0) : 0.f;
            float p1 = (mb & 2u)   ? __expf(e1) : 0.f;
            float p2 = (mb & 4u)   ? __expf(e2) : 0.f;
            float p3 = (mb & 8u)   ? __expf(e3) : 0.f;
            float p4 = (mb & 16u)  ? __expf(e4) : 0.f;
            float p5 = (mb & 32u)  ? __expf(e5) : 0.f;
            float p6 = (mb & 64u)  ? __expf(e6) : 0.f;
            float p7 = (mb & 128u) ? __expf(e7) : 0.f;
            denom += ((p0 + p1) + (p2 + p3)) + ((p4 + p5) + (p6 + p7));
            f16x2 q01 = __builtin_amdgcn_cvt_pkrtz(p0, p1);
            f16x2 q23 = __builtin_amdgcn_cvt_pkrtz(p2, p3);
            f16x2 q45 = __builtin_amdgcn_cvt_pkrtz(p4, p5);
            f16x2 q67 = __builtin_amdgcn_cvt_pkrtz(p6, p7);
            #pragma unroll
            for (int oo = 0; oo < FT; ++oo) {
                const f16x2* hp = (const f16x2*)&hb[oo * 120 + gg * 8];
                float a = acc[oo];
                a = __builtin_amdgcn_fdot2(q01, hp[0], a, false);
                a = __builtin_amdgcn_fdot2(q23, hp[1], a, false);
                a = __builtin_amdgcn_fdot2(q45, hp[2], a, false);
                a = __builtin_amdgcn_fdot2(q67, hp[3], a, false);
                acc[oo] = a;
            }
        }
        float inv = 1.f / denom;
        if constexpr (OUTMODE == 1) {
            float4* op = (float4*)&out[((size_t)g * NN + n) * FOUT + os];
            #pragma unroll
            for (int q4 = 0; q4 < FT / 4; ++q4) {
                float4 v;
                v.x = acc[4 * q4 + 0] * inv + bias[os + 4 * q4 + 0];
                v.y = acc[4 * q4 + 1] * inv + bias[os + 4 * q4 + 1];
                v.z = acc[4 * q4 + 2] * inv + bias[os + 4 * q4 + 2];
                v.w = acc[4 * q4 + 3] * inv + bias[os + 4 * q4 + 3];
                op[q4] = v;
            }
        } else {
            size_t base = ((size_t)g * NN + n) * FOUT + os;
            float4* op = (float4*)&out[base];
            const float4* mp = (const float4*)&mgate[base];
            #pragma unroll
            for (int q4 = 0; q4 < FT / 4; ++q4) {
                float4 mv = mp[q4];
                float4 v;
                v.x = (acc[4 * q4 + 0] * inv + bias[os + 4 * q4 + 0]) * mv.x;
                v.y = (acc[4 * q4 + 1] * inv + bias[os + 4 * q4 + 1]) * mv.y;
                v.z = (acc[4 * q4 + 2] * inv + bias[os + 4 * q4 + 2]) * mv.z;
                v.w = (acc[4 * q4 + 3] * inv + bias[os + 4 * q4 + 3]) * mv.w;
                op[q4] = v;
            }
        }
    }
}

// ---------------------------------------------------------------- pool + reparameterize
__global__ void pool_kernel(const float* __restrict__ g2, const float* __restrict__ eps,
                            float* __restrict__ z, float* __restrict__ dout) {
    int g = blockIdx.x;
    int c = threadIdx.x;
    __shared__ float s[2 * LATF];
    if (c < 2 * LATF) {
        float sum = 0.f;
        for (int n = 0; n < NN; ++n) sum += g2[((size_t)g * NN + n) * (2 * LATF) + c];
        s[c] = sum * (1.f / NN);
    }
    __syncthreads();
    if (c < LATF) {
        float mu = s[c], lv = s[LATF + c];
        dout[640000 + (size_t)g * LATF + c] = mu;
        dout[652800 + (size_t)g * LATF + c] = lv;
        z[(size_t)g * LATF + c] = mu + eps[(size_t)g * LATF + c] * __expf(0.5f * lv);
    }
}

// ---------------------------------------------------------------- launch
extern "C" void kernel_launch(void* const* d_in, const int* in_sizes, int n_in,
                              void* d_out, int out_size, void* d_ws, size_t ws_size,
                              hipStream_t stream) {
    const float* o     = (const float*)d_in[0];
    const float* aprev = (const float*)d_in[1];
    const float* mk    = (const float*)d_in[2];
    const float* eps   = (const float*)d_in[3];
    const int*   adj   = (const int*)d_in[4];
    const float* Wobs  = (const float*)d_in[5];
    const float* bobs  = (const float*)d_in[6];
    const float* Wpa   = (const float*)d_in[7];
    const float* bpa   = (const float*)d_in[8];
    const float* Wmk   = (const float*)d_in[9];
    const float* bmk   = (const float*)d_in[10];
    const float* idemb = (const float*)d_in[11];
    const float* lWih  = (const float*)d_in[12];
    const float* lWhh  = (const float*)d_in[13];
    const float* lbih  = (const float*)d_in[14];
    const float* lbhh  = (const float*)d_in[15];
    const float* e1w = (const float*)d_in[16]; const float* e1s = (const float*)d_in[17];
    const float* e1d = (const float*)d_in[18]; const float* e1b = (const float*)d_in[19];
    const float* e2w = (const float*)d_in[20]; const float* e2s = (const float*)d_in[21];
    const float* e2d = (const float*)d_in[22]; const float* e2b = (const float*)d_in[23];
    const float* d1w = (const float*)d_in[24]; const float* d1s = (const float*)d_in[25];
    const float* d1d = (const float*)d_in[26]; const float* d1b = (const float*)d_in[27];
    const float* d2w = (const float*)d_in[28]; const float* d2s = (const float*)d_in[29];
    const float* d2d = (const float*)d_in[30]; const float* d2b = (const float*)d_in[31];
    const float* d3w = (const float*)d_in[32]; const float* d3s = (const float*)d_in[33];
    const float* d3d = (const float*)d_in[34]; const float* d3b = (const float*)d_in[35];

    float* ws   = (float*)d_ws;
    float* emb  = ws;
    float* xenc = ws + 5120000;
    float* g1o  = ws + 10240000;
    float* g2o  = ws + 15360000;
    float* z    = ws + 17920000;
    float* d1o  = ws + 18000000;
    float* d2o  = ws + 23200000;
    unsigned long long* amask = (unsigned long long*)(ws + 30720000);
    float* out = (float*)d_out;

    adjmask_kernel<<<1, 128, 0, stream>>>(adj, amask);
    emb_kernel<<<BS * TT * NN, 64, 0, stream>>>(o, aprev, mk, Wobs, bobs, Wpa, bpa,
                                                Wmk, bmk, idemb, emb);
    lstm_mfma_kernel<<<100, 256, 0, stream>>>(emb, lWih, lWhh, lbih, lbhh, xenc);
    gat4h_kernel<0><<<800, 256, 0, stream>>>(xenc, nullptr, e1w, e1s, e1d, e1b, amask, g1o);
    gat_kernel<64, 0, 1, 32, 4, 1><<<800, 256, 0, stream>>>(g1o, nullptr, e2w, e2s, e2d, e2b,
                                                            amask, nullptr, g2o);
    pool_kernel<<<800, 64, 0, stream>>>(g2o, eps, z, out);
    gat4h_kernel<16><<<800, 256, 0, stream>>>(emb, z, d1w, d1s, d1d, d1b, amask, d1o);
    gat4h_kernel<0><<<800, 256, 0, stream>>>(d1o, nullptr, d2w, d2s, d2d, d2b, amask, d2o);
    gat_kernel<64, 0, 1, 8, 2, 2><<<800, 256, 0, stream>>>(d2o, nullptr, d3w, d3s, d3d, d3b,
                                                           amask, mk, out);
}